// Round 5
// baseline (137.014 us; speedup 1.0000x reference)
//
#include <hip/hip_runtime.h>

#define NB    256
#define SLEN  8192
#define LOG2S 13
#define TOPK  10
#define RES_REAL ((size_t)20971520)   // residual real parts follow bf real parts

typedef unsigned long long u64;
typedef unsigned int u32;

// winners: {k as int bits, ar, ai, 0} — fully rewritten by every call
__device__ float4 g_win[NB * TOPK];

// v_sin_f32/v_cos_f32 take REVOLUTIONS; args in (-0.1, 1.0), no reduction.
__device__ __forceinline__ float sin_rev(float p) { return __builtin_amdgcn_sinf(p); }
__device__ __forceinline__ float cos_rev(float p) { return __builtin_amdgcn_cosf(p); }

// Packed sort key: [quantized mag^2 bits | 8191 - idx]. Quantizing mag^2 to
// 10 mantissa bits makes conjugate-pair magnitudes (equal up to FFT rounding)
// compare EQUAL, so the tie falls to the index part: lower index wins —
// matching numpy's stable argsort(-mag). (Pair order matters: swapped rows
// change Re(bf) by ~0.5|row| because the 1e-5 phase offset isn't conjugated.)
__device__ __forceinline__ u64 pack_key(float m2, int i) {
  u32 qb = __float_as_uint(m2) & 0xFFFFE000u;
  return ((u64)qb << 32) | (u32)(SLEN - 1 - i);
}

// ---------------------------------------------------------------------------
// Kernel A: 8192-pt radix-2 FFT in LDS (1024 thr) + top-10 with 3 barriers.
// ---------------------------------------------------------------------------
__global__ __launch_bounds__(1024, 1)
void fft_topk(const float* __restrict__ x) {
  __shared__ __align__(16) float re[SLEN];
  __shared__ __align__(16) float im[SLEN];

  const int b = blockIdx.x;
  const int t = threadIdx.x;
  const int lane = t & 63;
  const int wid  = t >> 6;                      // 16 waves
  const float* xb = x + (size_t)b * SLEN;

  for (int i = t; i < SLEN; i += 1024) { re[i] = xb[i]; im[i] = 0.f; }
  __syncthreads();

  for (int i = t; i < SLEN; i += 1024) {
    int j = (int)(__brev((u32)i) >> (32 - LOG2S));
    if (i < j) { float tmp = re[i]; re[i] = re[j]; re[j] = tmp; }
  }
  __syncthreads();

  for (int stage = 1; stage <= LOG2S; ++stage) {
    const int half = 1 << (stage - 1);
    const float invm = 1.f / (float)(1 << stage);
    for (int bfi = t; bfi < SLEN / 2; bfi += 1024) {
      const int pos = bfi & (half - 1);
      const int i = ((bfi >> (stage - 1)) << stage) + pos;
      const int j = i + half;
      const float p = (float)pos * invm;        // [0, 0.5) revolutions
      const float c  = cos_rev(p);
      const float sn = -sin_rev(p);
      const float vr = re[j], vi = im[j];
      const float tr = vr * c - vi * sn;
      const float ti = vr * sn + vi * c;
      const float ur = re[i], ui = im[i];
      re[i] = ur + tr; im[i] = ui + ti;
      re[j] = ur - tr; im[j] = ui - ti;
    }
    __syncthreads();
  }

  // ---- mag^2 keys: 8 elements/thread, register-resident ----
  u64 key[8];
#pragma unroll
  for (int q = 0; q < 8; ++q) {
    const int i = t + (q << 10);
    key[q] = pack_key(re[i] * re[i] + im[i] * im[i], i);
  }

  // ---- per-wave top-10, wave-synchronous (no barriers) ----
  u64 winkey[TOPK];
#pragma unroll
  for (int r = 0; r < TOPK; ++r) {
    u64 best = key[0];
#pragma unroll
    for (int q = 1; q < 8; ++q) best = (key[q] > best) ? key[q] : best;
    for (int off = 1; off < 64; off <<= 1) {
      const u64 o = __shfl_xor(best, off);      // all lanes end with the max
      best = (o > best) ? o : best;
    }
#pragma unroll
    for (int q = 0; q < 8; ++q) if (key[q] == best) key[q] = 0;  // unique owner
    winkey[r] = best;
  }

  // lanes 0..9 capture their wave's candidate j = lane: (key, re, im)
  u64 mykey = 0;
#pragma unroll
  for (int j = 0; j < TOPK; ++j) if (lane == j) mykey = winkey[j];
  float mre = 0.f, mim = 0.f;
  if (lane < TOPK) {
    const int k = SLEN - 1 - (int)(mykey & 0x1FFFu);
    mre = re[k]; mim = im[k];
  }
  __syncthreads();                              // all re/im reads complete
  if (lane < TOPK)
    ((float4*)re)[wid * TOPK + lane] = make_float4(
        __uint_as_float((u32)mykey), __uint_as_float((u32)(mykey >> 32)), mre, mim);
  __syncthreads();                              // 160 candidates visible

  // ---- wave 0 merges 160 candidates -> 10 winners (wave-synchronous) ----
  if (wid == 0) {
    u64 k0, k1, k2 = 0;
    float r0, i0, r1, i1, r2 = 0.f, i2 = 0.f;
    float4 c = ((float4*)re)[lane];
    k0 = ((u64)__float_as_uint(c.y) << 32) | __float_as_uint(c.x); r0 = c.z; i0 = c.w;
    c = ((float4*)re)[lane + 64];
    k1 = ((u64)__float_as_uint(c.y) << 32) | __float_as_uint(c.x); r1 = c.z; i1 = c.w;
    if (lane < 32) {
      c = ((float4*)re)[lane + 128];
      k2 = ((u64)__float_as_uint(c.y) << 32) | __float_as_uint(c.x); r2 = c.z; i2 = c.w;
    }
#pragma unroll
    for (int r = 0; r < TOPK; ++r) {
      u64 best = (k0 > k1) ? k0 : k1;
      best = (k2 > best) ? k2 : best;
      for (int off = 1; off < 64; off <<= 1) {
        const u64 o = __shfl_xor(best, off);
        best = (o > best) ? o : best;
      }
      float cre = 0.f, cim = 0.f; bool own = false;
      if (k0 == best)      { own = true; cre = r0; cim = i0; k0 = 0; }
      else if (k1 == best) { own = true; cre = r1; cim = i1; k1 = 0; }
      else if (k2 == best) { own = true; cre = r2; cim = i2; k2 = 0; }
      if (own) {                                 // exactly one lane
        const int k = SLEN - 1 - (int)(best & 0x1FFFu);
        const float rr = cre * (1.f / (float)SLEN);   // raw/S (ortho twice)
        const float ii = cim * (1.f / (float)SLEN);
        const float pr = -1e-5f * (float)k;           // revolutions
        const float cp = cos_rev(pr), sp = sin_rev(pr);
        g_win[b * TOPK + r] =
            make_float4(__int_as_float(k), rr * cp - ii * sp, rr * sp + ii * cp, 0.f);
      }
    }
  }
}

// ---------------------------------------------------------------------------
// Kernel B: real parts of bf and residual. 2048 blocks x 256 thr (full
// occupancy) -> stores stream at the HBM write ceiling.
//   Re bf[b,j,s] = ar*cos(2pi k m/S) - ai*sin(2pi k m/S), m = max(s,1)
//   res[b,s]     = x[b,s] - sum_j Re bf
// ---------------------------------------------------------------------------
__global__ __launch_bounds__(256)
void gen_out(const float* __restrict__ x, float* __restrict__ out, size_t cap) {
  __shared__ float4 w[TOPK];
  const int blk = blockIdx.x;
  const int b = blk >> 3;                        // 8 chunks per batch
  const int chunk = blk & 7;
  const int t = threadIdx.x;
  if (t < TOPK) w[t] = g_win[b * TOPK + t];
  __syncthreads();

  const int s0 = chunk * 1024 + t * 4;           // 4 consecutive s per thread
  const float4 xv = *(const float4*)(x + (size_t)b * SLEN + s0);
  float a0 = 0.f, a1 = 0.f, a2 = 0.f, a3 = 0.f;
  const size_t bfbase = (size_t)b * TOPK * SLEN;

#pragma unroll
  for (int j = 0; j < TOPK; ++j) {
    const int k = __float_as_int(w[j].x);
    const float ar = w[j].y, ai = w[j].z;
    float br[4];
#pragma unroll
    for (int q = 0; q < 4; ++q) {
      const int s = s0 + q;
      const int m = (s == 0) ? 1 : s;
      const float p = (float)((k * m) & (SLEN - 1)) * (1.f / (float)SLEN);
      br[q] = ar * cos_rev(p) - ai * sin_rev(p);
    }
    a0 += br[0]; a1 += br[1]; a2 += br[2]; a3 += br[3];
    const size_t o = bfbase + (size_t)j * SLEN + s0;
    if (o + 4 <= cap)
      *(float4*)(out + o) = make_float4(br[0], br[1], br[2], br[3]);
  }
  const size_t o = RES_REAL + (size_t)b * SLEN + s0;
  if (o + 4 <= cap)
    *(float4*)(out + o) = make_float4(xv.x - a0, xv.y - a1, xv.z - a2, xv.w - a3);
}

extern "C" void kernel_launch(void* const* d_in, const int* in_sizes, int n_in,
                              void* d_out, int out_size, void* d_ws, size_t ws_size,
                              hipStream_t stream) {
  const float* x = (const float*)d_in[0];
  float* out = (float*)d_out;
  fft_topk<<<NB, 1024, 0, stream>>>(x);
  gen_out<<<NB * 8, 256, 0, stream>>>(x, out, (size_t)out_size);
}